// Round 1
// 422.658 us; speedup vs baseline: 3.3345x; 3.3345x over previous
//
#include <hip/hip_runtime.h>

// FAVOR+ attention, B=4 L=4096 D=1024 H=16 d=64 m=256, fp32 in/out.
// MFMA rewrite: all matmuls via v_mfma_f32_16x16x32_bf16 with split-bf16
// (hi+lo, 3 products) fp32 emulation. stab=0 (verified equivalent earlier).
// Pipeline: prep (W frags + zero kvx) -> kv (proj+exp, k'^T@[V|1] via MFMA,
// atomic partial sums) -> fragk (kvx -> hi/lo B-frags) -> out (proj+exp,
// q'@kvx via MFMA; denominator = column 64 of kvx).

typedef unsigned short u16;
typedef __attribute__((ext_vector_type(8))) short s8v;   // 8 bf16 (4 VGPR)
typedef __attribute__((ext_vector_type(4))) float f4v;   // C/D frag

#define NB 4
#define NL 4096
#define ND 1024
#define NH 16
#define HDIM 64
#define NM 256

#define SCALE 0.17677669529663687f  // 1024^-0.25
#define RSQM 0.0625f                // 256^-0.5
#define FEPS 1e-4f
#define ECLAMP 80.0f

#define MFMA16(a, b, c) __builtin_amdgcn_mfma_f32_16x16x32_bf16((a), (b), (c), 0, 0, 0)

__device__ __forceinline__ u16 f2bf(float x) {  // round-to-nearest-even bf16
  unsigned u = __float_as_uint(x);
  u += 0x7FFFu + ((u >> 16) & 1u);
  return (u16)(u >> 16);
}
__device__ __forceinline__ float bf2f(u16 b) {
  return __uint_as_float(((unsigned)b) << 16);
}

// Build one A-frag pair (hi/lo) from 8 scaled floats; accumulate sum of squares.
__device__ __forceinline__ void mk2(const float4& a, const float4& b, float sc,
                                    s8v& hi, s8v& lo, float& ss) {
  float f[8] = {a.x * sc, a.y * sc, a.z * sc, a.w * sc,
                b.x * sc, b.y * sc, b.z * sc, b.w * sc};
#pragma unroll
  for (int e = 0; e < 8; e++) {
    ss = fmaf(f[e], f[e], ss);
    u16 h = f2bf(f[e]);
    u16 l = f2bf(f[e] - bf2f(h));
    hi[e] = (short)h;
    lo[e] = (short)l;
  }
}

// W B-fragments: layout [kk(2)][mt(16)][lane(64)][e(8)].
// B[k][j]: j = mt*16 + (lane&15), k = kk*32 + (lane>>4)*8 + e, value = W[j][k].
// Also zeroes the kvx accumulator (re-zeroed every launch; atomics add into it).
__global__ void prep_kernel(const float* __restrict__ wp, u16* __restrict__ WfH,
                            u16* __restrict__ WfL, float* __restrict__ kvx) {
  const int idx = blockIdx.x * 512 + threadIdx.x;  // grid 32 -> 0..16383
  const int e = idx & 7, ln = (idx >> 3) & 63, mt = (idx >> 9) & 15, kk = idx >> 13;
  const int m = mt * 16 + (ln & 15);
  const int d = kk * 32 + ((ln >> 4) << 3) + e;
  const float x = wp[m * HDIM + d];
  const u16 hh = f2bf(x);
  WfH[idx] = hh;
  WfL[idx] = f2bf(x - bf2f(hh));
  for (int i = idx; i < 64 * 256 * 80; i += 16384) kvx[i] = 0.f;
}

// Grid 512 = (bh 64) x (chunk 8); 512 threads = 8 waves. Each block: 512 rows
// of K/V in 16 iters of 32 rows. Stage A: proj = K^ @ W^T (A-frags from global,
// row norms via shfl), exp -> k' hi/lo into LDS kp[m][l]. Stage B:
// kv[256][80] += k'^T @ [V | 1 | 0..]; ksum lands in column 64.
__global__ __launch_bounds__(512, 4) void kv_kernel(
    const float* __restrict__ kg, const float* __restrict__ vg,
    const u16* __restrict__ WfH, const u16* __restrict__ WfL,
    float* __restrict__ kvx) {
  const int bh = blockIdx.x >> 3, ch = blockIdx.x & 7;
  const int b = bh >> 4, h = bh & 15;
  const int tid = threadIdx.x, lane = tid & 63, w = tid >> 6;
  const int l15 = lane & 15, g = lane >> 4;

  __shared__ __align__(16) u16 kpH[256][40];  // [m][l], stride 80 B
  __shared__ __align__(16) u16 kpL[256][40];
  __shared__ __align__(16) float Vl[32][72];  // stride 72 f32 -> 2-way banks

  const int rt = w & 1, mg = w >> 1;  // stage A: rows rt*16.., m-tiles mg*4..
  const int mtb = 2 * w;              // stage B m-tiles {2w, 2w+1}

  f4v zero4 = {0.f, 0.f, 0.f, 0.f};
  f4v acc[2][5];
#pragma unroll
  for (int i = 0; i < 2; i++)
#pragma unroll
    for (int j = 0; j < 5; j++) acc[i][j] = zero4;

  s8v oneh = {0, 0, 0, 0, 0, 0, 0, 0};  // ones-column B-frag (col 64 only)
  if (l15 == 0) {
#pragma unroll
    for (int e = 0; e < 8; e++) oneh[e] = (short)0x3F80;
  }

  const int svr = tid >> 4, svc = (tid & 15) * 4;  // V stager: 32x16 float4

  for (int it = 0; it < 16; it++) {
    const int rbase = ch * 512 + it * 32;
    // early V load (T14: issue before compute, LDS-write after barrier)
    const float4 vv =
        *(const float4*)(vg + (size_t)(b * NL + rbase + svr) * ND + h * HDIM + svc);
    // A1 frags straight from global K (16-lane x 32B chunks; L1 merges)
    const float* kb = kg + (size_t)(b * NL + rbase + rt * 16 + l15) * ND + h * HDIM;
    const float4 ka0 = *(const float4*)(kb + g * 8);
    const float4 ka1 = *(const float4*)(kb + g * 8 + 4);
    const float4 ka2 = *(const float4*)(kb + 32 + g * 8);
    const float4 ka3 = *(const float4*)(kb + 32 + g * 8 + 4);
    s8v a0h, a0l, a1h, a1l;
    float ss = 0.f;
    mk2(ka0, ka1, SCALE, a0h, a0l, ss);
    mk2(ka2, ka3, SCALE, a1h, a1l, ss);
    ss += __shfl_xor(ss, 16);
    ss += __shfl_xor(ss, 32);              // full ||k^row||^2, row = rt*16 + l15
    const float cneg = -0.5f * ss;

    // LICM-breaker: keep W-frag loads inside the loop (hoisting = 64 VGPRs)
    int itz = it;
    asm volatile("" : "+v"(itz));
    const u16* WfHp = WfH + (itz & 0x7FFF0000);  // == WfH at runtime
    const u16* WfLp = WfL + (itz & 0x7FFF0000);

    u16 hs[4][4], ls[4][4];
#pragma unroll
    for (int mi = 0; mi < 4; mi++) {
      const int mt = mg * 4 + mi;
      const s8v b0h = *(const s8v*)(WfHp + (size_t)(mt * 64 + lane) * 8);
      const s8v b0l = *(const s8v*)(WfLp + (size_t)(mt * 64 + lane) * 8);
      const s8v b1h = *(const s8v*)(WfHp + (size_t)((16 + mt) * 64 + lane) * 8);
      const s8v b1l = *(const s8v*)(WfLp + (size_t)((16 + mt) * 64 + lane) * 8);
      f4v p = zero4;
      p = MFMA16(a0h, b0h, p);
      p = MFMA16(a1h, b1h, p);
      p = MFMA16(a0h, b0l, p);
      p = MFMA16(a1h, b1l, p);
      p = MFMA16(a0l, b0h, p);
      p = MFMA16(a1l, b1h, p);
#pragma unroll
      for (int r = 0; r < 4; r++) {
        const float cc = __shfl(cneg, 4 * g + r);  // norm of C-row rt*16+4g+r
        const float arg = fminf(p[r] + cc, ECLAMP);
        const float kv_ = RSQM * __expf(arg) + (RSQM * FEPS);
        const u16 hh = f2bf(kv_);
        hs[mi][r] = hh;
        ls[mi][r] = f2bf(kv_ - bf2f(hh));
      }
    }
    __syncthreads();  // previous iter's stage-B readers are done
#pragma unroll
    for (int mi = 0; mi < 4; mi++) {
      const int m = (mg * 4 + mi) * 16 + l15;
      *(ushort4*)&kpH[m][rt * 16 + 4 * g] =
          make_ushort4(hs[mi][0], hs[mi][1], hs[mi][2], hs[mi][3]);
      *(ushort4*)&kpL[m][rt * 16 + 4 * g] =
          make_ushort4(ls[mi][0], ls[mi][1], ls[mi][2], ls[mi][3]);
    }
    *(float4*)&Vl[svr][svc] = vv;
    __syncthreads();

    // stage B: A2 = k'^T frags, one ds_read_b128 each
    const s8v A0h = *(const s8v*)&kpH[mtb * 16 + l15][8 * g];
    const s8v A0l = *(const s8v*)&kpL[mtb * 16 + l15][8 * g];
    const s8v A1h = *(const s8v*)&kpH[(mtb + 1) * 16 + l15][8 * g];
    const s8v A1l = *(const s8v*)&kpL[(mtb + 1) * 16 + l15][8 * g];
#pragma unroll
    for (int ct = 0; ct < 4; ct++) {
      s8v vh, vl;
#pragma unroll
      for (int e = 0; e < 8; e++) {
        const float x = Vl[8 * g + e][ct * 16 + l15];
        const u16 hh = f2bf(x);
        vh[e] = (short)hh;
        vl[e] = (short)f2bf(x - bf2f(hh));
      }
      acc[0][ct] = MFMA16(A0h, vh, acc[0][ct]);
      acc[0][ct] = MFMA16(A0h, vl, acc[0][ct]);
      acc[0][ct] = MFMA16(A0l, vh, acc[0][ct]);
      acc[1][ct] = MFMA16(A1h, vh, acc[1][ct]);
      acc[1][ct] = MFMA16(A1h, vl, acc[1][ct]);
      acc[1][ct] = MFMA16(A1l, vh, acc[1][ct]);
    }
    acc[0][4] = MFMA16(A0h, oneh, acc[0][4]);  // ksum column (ones, lo = 0)
    acc[0][4] = MFMA16(A0l, oneh, acc[0][4]);
    acc[1][4] = MFMA16(A1h, oneh, acc[1][4]);
    acc[1][4] = MFMA16(A1l, oneh, acc[1][4]);
  }

  float* kvb = kvx + (size_t)bh * (256 * 80);
#pragma unroll
  for (int mi = 0; mi < 2; mi++)
#pragma unroll
    for (int ct = 0; ct < 5; ct++)
#pragma unroll
      for (int r = 0; r < 4; r++) {
        const int m = (mtb + mi) * 16 + 4 * g + r;
        const int c = ct * 16 + l15;
        atomicAdd(&kvb[m * 80 + c], acc[mi][ct][r]);
      }
}

// kvx (summed) -> hi/lo B-fragments, layout [bh][kk(8)][ct(5)][lane(64)][e(8)].
// B[k][j]: k = kk*32 + (lane>>4)*8 + e (the m axis), j = ct*16 + (lane&15).
__global__ __launch_bounds__(512) void fragk_kernel(const float* __restrict__ kvx,
                                                    u16* __restrict__ kvfH,
                                                    u16* __restrict__ kvfL) {
  const int bh = blockIdx.x;
  const float* kb = kvx + (size_t)bh * (256 * 80);
  for (int f = threadIdx.x; f < 20480; f += 512) {
    const int kk = f / 2560;
    const int r1 = f - kk * 2560;
    const int ct = r1 >> 9;
    const int r2 = r1 & 511;
    const int ln = r2 >> 3, e = r2 & 7;
    const int m = kk * 32 + ((ln >> 4) << 3) + e;
    const int c = ct * 16 + (ln & 15);
    const float x = kb[m * 80 + c];
    const u16 hh = f2bf(x);
    kvfH[(size_t)bh * 20480 + f] = hh;
    kvfL[(size_t)bh * 20480 + f] = f2bf(x - bf2f(hh));
  }
}

// Grid 4096 = (bh 64) x (64-row L-tile 64); 512 threads = 8 waves.
// Stage A: q' = RSQM*exp(proj)+RSQM*eps -> hi/lo into qp[l][m] (stride 264).
// Stage B: out[64][80] = q' @ kvx; cols 0-63 = numerator, col 64 = denominator.
__global__ __launch_bounds__(512, 4) void out_kernel(
    const float* __restrict__ qg, const u16* __restrict__ WfH,
    const u16* __restrict__ WfL, const u16* __restrict__ kvfH,
    const u16* __restrict__ kvfL, float* __restrict__ outp) {
  const int bh = blockIdx.x >> 6, lt = blockIdx.x & 63;
  const int b = bh >> 4, h = bh & 15;
  const int tid = threadIdx.x, lane = tid & 63, w = tid >> 6;
  const int l15 = lane & 15, g = lane >> 4;

  __shared__ __align__(16) u16 qpH[64][264];  // [l][m], stride 528 B
  __shared__ __align__(16) u16 qpL[64][264];
  __shared__ float dinv[64];

  const int rt = w & 3, mh = w >> 2;

  {  // ---- stage A ----
    const float* qb = qg + (size_t)(b * NL + lt * 64 + rt * 16 + l15) * ND + h * HDIM;
    const float4 qa0 = *(const float4*)(qb + g * 8);
    const float4 qa1 = *(const float4*)(qb + g * 8 + 4);
    const float4 qa2 = *(const float4*)(qb + 32 + g * 8);
    const float4 qa3 = *(const float4*)(qb + 32 + g * 8 + 4);
    s8v a0h, a0l, a1h, a1l;
    float ss = 0.f;
    mk2(qa0, qa1, SCALE, a0h, a0l, ss);
    mk2(qa2, qa3, SCALE, a1h, a1l, ss);
    f4v zero4 = {0.f, 0.f, 0.f, 0.f};
#pragma unroll
    for (int mi = 0; mi < 8; mi++) {
      const int mt = mh * 8 + mi;
      const s8v b0h = *(const s8v*)(WfH + (size_t)(mt * 64 + lane) * 8);
      const s8v b0l = *(const s8v*)(WfL + (size_t)(mt * 64 + lane) * 8);
      const s8v b1h = *(const s8v*)(WfH + (size_t)((16 + mt) * 64 + lane) * 8);
      const s8v b1l = *(const s8v*)(WfL + (size_t)((16 + mt) * 64 + lane) * 8);
      f4v p = zero4;
      p = MFMA16(a0h, b0h, p);
      p = MFMA16(a1h, b1h, p);
      p = MFMA16(a0h, b0l, p);
      p = MFMA16(a1h, b1l, p);
      p = MFMA16(a0l, b0h, p);
      p = MFMA16(a1l, b1h, p);
#pragma unroll
      for (int r = 0; r < 4; r++) {
        // queries: stab = h cancels exactly -> q' = RSQM*exp(proj) + RSQM*eps
        const float arg = fminf(p[r], ECLAMP);
        const float qv = RSQM * __expf(arg) + (RSQM * FEPS);
        const u16 hh = f2bf(qv);
        qpH[rt * 16 + 4 * g + r][mt * 16 + l15] = hh;
        qpL[rt * 16 + 4 * g + r][mt * 16 + l15] = f2bf(qv - bf2f(hh));
      }
    }
  }
  __syncthreads();

  // ---- stage B ---- waves w<4: cts {0,1,4} (rt rows); w>=4: cts {2,3}
  const int ctA = (w < 4) ? 0 : 2;
  const int ctB = ctA + 1;
  f4v o0 = {0.f, 0.f, 0.f, 0.f}, o1 = o0, o2 = o0;
  const size_t fb = (size_t)bh * (8 * 5 * 512);
#pragma unroll
  for (int kk = 0; kk < 8; kk++) {
    const s8v A2h = *(const s8v*)&qpH[rt * 16 + l15][kk * 32 + 8 * g];
    const s8v A2l = *(const s8v*)&qpL[rt * 16 + l15][kk * 32 + 8 * g];
    const size_t bA = fb + (size_t)((kk * 5 + ctA) * 64 + lane) * 8;
    const s8v BAh = *(const s8v*)(kvfH + bA);
    const s8v BAl = *(const s8v*)(kvfL + bA);
    o0 = MFMA16(A2h, BAh, o0);
    o0 = MFMA16(A2h, BAl, o0);
    o0 = MFMA16(A2l, BAh, o0);
    const size_t bB = fb + (size_t)((kk * 5 + ctB) * 64 + lane) * 8;
    const s8v BBh = *(const s8v*)(kvfH + bB);
    const s8v BBl = *(const s8v*)(kvfL + bB);
    o1 = MFMA16(A2h, BBh, o1);
    o1 = MFMA16(A2h, BBl, o1);
    o1 = MFMA16(A2l, BBh, o1);
    if (w < 4) {
      const size_t bC = fb + (size_t)((kk * 5 + 4) * 64 + lane) * 8;
      const s8v BCh = *(const s8v*)(kvfH + bC);
      const s8v BCl = *(const s8v*)(kvfL + bC);
      o2 = MFMA16(A2h, BCh, o2);
      o2 = MFMA16(A2h, BCl, o2);
      o2 = MFMA16(A2l, BCh, o2);
    }
  }
  if (w < 4 && l15 == 0) {  // denominator = column 64
#pragma unroll
    for (int r = 0; r < 4; r++) {
      float d = o2[r];
      if (fabsf(d) <= FEPS) d += 2.0f * FEPS;
      dinv[rt * 16 + 4 * g + r] = 1.0f / d;
    }
  }
  __syncthreads();
  {
    float* ob = outp + (size_t)(b * NL + lt * 64) * ND + h * HDIM;
#pragma unroll
    for (int r = 0; r < 4; r++) {
      const int row = rt * 16 + 4 * g + r;
      const float di = dinv[row];
      ob[(size_t)row * ND + ctA * 16 + l15] = o0[r] * di;
      ob[(size_t)row * ND + ctB * 16 + l15] = o1[r] * di;
    }
  }
}

extern "C" void kernel_launch(void* const* d_in, const int* in_sizes, int n_in,
                              void* d_out, int out_size, void* d_ws, size_t ws_size,
                              hipStream_t stream) {
  const float* q = (const float*)d_in[0];
  const float* k = (const float*)d_in[1];
  const float* v = (const float*)d_in[2];
  const float* w = (const float*)d_in[3];
  float* out = (float*)d_out;

  // workspace: WfH 32KB | WfL 32KB | kvx 5.24MB | kvfH 2.62MB | kvfL 2.62MB
  // total ~10.1 MB
  u16* WfH = (u16*)d_ws;
  u16* WfL = WfH + 16384;
  float* kvx = (float*)((char*)d_ws + 65536);
  u16* kvfH = (u16*)((char*)d_ws + 65536 + (size_t)64 * 256 * 80 * 4);
  u16* kvfL = kvfH + (size_t)64 * 20480;

  prep_kernel<<<32, 512, 0, stream>>>(w, WfH, WfL, kvx);
  kv_kernel<<<512, 512, 0, stream>>>(k, v, WfH, WfL, kvx);
  fragk_kernel<<<64, 512, 0, stream>>>(kvx, kvfH, kvfL);
  out_kernel<<<4096, 512, 0, stream>>>(q, WfH, WfL, kvfH, kvfL, out);
}

// Round 2
// 398.976 us; speedup vs baseline: 3.5324x; 1.0594x over previous
//
#include <hip/hip_runtime.h>

// FAVOR+ attention, B=4 L=4096 D=1024 H=16 d=64 m=256, fp32 in/out.
// MFMA rewrite: all matmuls via v_mfma_f32_16x16x32_bf16 with split-bf16
// (hi+lo, 3 products) fp32 emulation. stab=0 (verified equivalent earlier).
// R2: V staged directly as shared bf16 hi/lo B-fragments (1x conversion,
// conflict-free b128), truncation-based hi/lo split (~half the VALU of RNE).
// Pipeline: prep (W frags + zero kvx) -> kv (proj+exp, k'^T@[V|1] via MFMA,
// atomic partial sums) -> fragk (kvx -> hi/lo B-frags) -> out (proj+exp,
// q'@kvx via MFMA; denominator = column 64 of kvx).

typedef unsigned short u16;
typedef __attribute__((ext_vector_type(8))) short s8v;   // 8 bf16 (4 VGPR)
typedef __attribute__((ext_vector_type(4))) float f4v;   // C/D frag

#define NB 4
#define NL 4096
#define ND 1024
#define NH 16
#define HDIM 64
#define NM 256

#define SCALE 0.17677669529663687f  // 1024^-0.25
#define RSQM 0.0625f                // 256^-0.5
#define FEPS 1e-4f
#define ECLAMP 80.0f

#define MFMA16(a, b, c) __builtin_amdgcn_mfma_f32_16x16x32_bf16((a), (b), (c), 0, 0, 0)

__device__ __forceinline__ u16 f2bf(float x) {  // RNE bf16 (prep/fragk only)
  unsigned u = __float_as_uint(x);
  u += 0x7FFFu + ((u >> 16) & 1u);
  return (u16)(u >> 16);
}
__device__ __forceinline__ float bf2f(u16 b) {
  return __uint_as_float(((unsigned)b) << 16);
}
// Truncation split: hi = top 16 bits; residual x - hi is exact in fp32,
// its truncation error is ~2^-16 relative to x. ~3 VALU ops vs ~8 for RNE.
__device__ __forceinline__ u16 bhi(float x) {
  return (u16)(__float_as_uint(x) >> 16);
}
__device__ __forceinline__ float bhif(float x) {
  return __uint_as_float(__float_as_uint(x) & 0xFFFF0000u);
}

// Build one A-frag pair (hi/lo, trunc) from 8 scaled floats; accumulate sum sq.
__device__ __forceinline__ void mk2t(const float4& a, const float4& b, float sc,
                                     s8v& hi, s8v& lo, float& ss) {
  float f[8] = {a.x * sc, a.y * sc, a.z * sc, a.w * sc,
                b.x * sc, b.y * sc, b.z * sc, b.w * sc};
#pragma unroll
  for (int e = 0; e < 8; e++) {
    ss = fmaf(f[e], f[e], ss);
    hi[e] = (short)bhi(f[e]);
    lo[e] = (short)bhi(f[e] - bhif(f[e]));
  }
}

// W B-fragments: layout [kk(2)][mt(16)][lane(64)][e(8)].
// B[k][j]: j = mt*16 + (lane&15), k = kk*32 + (lane>>4)*8 + e, value = W[j][k].
// Also zeroes the kvx accumulator (re-zeroed every launch; atomics add into it).
__global__ void prep_kernel(const float* __restrict__ wp, u16* __restrict__ WfH,
                            u16* __restrict__ WfL, float* __restrict__ kvx) {
  const int idx = blockIdx.x * 512 + threadIdx.x;  // grid 32 -> 0..16383
  const int e = idx & 7, ln = (idx >> 3) & 63, mt = (idx >> 9) & 15, kk = idx >> 13;
  const int m = mt * 16 + (ln & 15);
  const int d = kk * 32 + ((ln >> 4) << 3) + e;
  const float x = wp[m * HDIM + d];
  const u16 hh = f2bf(x);
  WfH[idx] = hh;
  WfL[idx] = f2bf(x - bf2f(hh));
  for (int i = idx; i < 64 * 256 * 80; i += 16384) kvx[i] = 0.f;
}

// Grid 512 = (bh 64) x (chunk 8); 512 threads = 8 waves. Each block: 512 rows
// of K/V in 16 iters of 32 rows. Stage A: proj = K^ @ W^T (A-frags from global,
// row norms via shfl), exp -> k' hi/lo into LDS kp[m][l]. V fragments built
// once per tile (wave w: ct = w&3, hi/lo = w>>2) into VfH/VfL. Stage B:
// kv[256][80] += k'^T @ [V | 1 | 0..]; ksum lands in column 64.
__global__ __launch_bounds__(512, 4) void kv_kernel(
    const float* __restrict__ kg, const float* __restrict__ vg,
    const u16* __restrict__ WfH, const u16* __restrict__ WfL,
    float* __restrict__ kvx) {
  const int bh = blockIdx.x >> 3, ch = blockIdx.x & 7;
  const int b = bh >> 4, h = bh & 15;
  const int tid = threadIdx.x, lane = tid & 63, w = tid >> 6;
  const int l15 = lane & 15, g = lane >> 4;

  __shared__ __align__(16) u16 kpH[256][40];    // [m][l], stride 80 B
  __shared__ __align__(16) u16 kpL[256][40];
  __shared__ __align__(16) u16 VfH[4][64][8];   // V B-frags, per ct
  __shared__ __align__(16) u16 VfL[4][64][8];

  const int rt = w & 1, mg = w >> 1;  // stage A: rows rt*16.., m-tiles mg*4..
  const int mtb = 2 * w;              // stage B m-tiles {2w, 2w+1}
  const int vct = w & 3, vhl = w >> 2;  // V-frag duty: column tile, hi-or-lo

  f4v zero4 = {0.f, 0.f, 0.f, 0.f};
  f4v acc[2][5];
#pragma unroll
  for (int i = 0; i < 2; i++)
#pragma unroll
    for (int j = 0; j < 5; j++) acc[i][j] = zero4;

  s8v oneh = {0, 0, 0, 0, 0, 0, 0, 0};  // ones-column B-frag (col 64 only)
  if (l15 == 0) {
#pragma unroll
    for (int e = 0; e < 8; e++) oneh[e] = (short)0x3F80;
  }

  for (int it = 0; it < 16; it++) {
    const int rbase = ch * 512 + it * 32;
    // V scalar loads for this wave's fragment: V[rbase+8g+e][vct*16+l15].
    // Per instruction: 4 x 64B contiguous segments (16-lane groups) — L1 merges.
    const float* vb =
        vg + (size_t)(b * NL + rbase + 8 * g) * ND + h * HDIM + vct * 16 + l15;
    float vx[8];
#pragma unroll
    for (int e = 0; e < 8; e++) vx[e] = vb[(size_t)e * ND];
    // K A-frags straight from global (16-lane x 32B chunks; L1 merges)
    const float* kb = kg + (size_t)(b * NL + rbase + rt * 16 + l15) * ND + h * HDIM;
    const float4 ka0 = *(const float4*)(kb + g * 8);
    const float4 ka1 = *(const float4*)(kb + g * 8 + 4);
    const float4 ka2 = *(const float4*)(kb + 32 + g * 8);
    const float4 ka3 = *(const float4*)(kb + 32 + g * 8 + 4);
    s8v a0h, a0l, a1h, a1l;
    float ss = 0.f;
    mk2t(ka0, ka1, SCALE, a0h, a0l, ss);
    mk2t(ka2, ka3, SCALE, a1h, a1l, ss);
    ss += __shfl_xor(ss, 16);
    ss += __shfl_xor(ss, 32);              // full ||k^row||^2, row = rt*16 + l15
    const float cneg = -0.5f * ss;
    // norm of C-rows rt*16+4g+r, hoisted out of the mi loop
    float ccr[4];
#pragma unroll
    for (int r = 0; r < 4; r++) ccr[r] = __shfl(cneg, 4 * g + r);

    // build this wave's V fragment (trunc split)
    s8v vf;
    if (vhl == 0) {
#pragma unroll
      for (int e = 0; e < 8; e++) vf[e] = (short)bhi(vx[e]);
    } else {
#pragma unroll
      for (int e = 0; e < 8; e++) vf[e] = (short)bhi(vx[e] - bhif(vx[e]));
    }

    // LICM-breaker: keep W-frag loads inside the loop (hoisting = 64 VGPRs)
    int itz = it;
    asm volatile("" : "+v"(itz));
    const u16* WfHp = WfH + (itz & 0x7FFF0000);  // == WfH at runtime
    const u16* WfLp = WfL + (itz & 0x7FFF0000);

    u16 hs[4][4], ls[4][4];
#pragma unroll
    for (int mi = 0; mi < 4; mi++) {
      const int mt = mg * 4 + mi;
      const s8v b0h = *(const s8v*)(WfHp + (size_t)(mt * 64 + lane) * 8);
      const s8v b0l = *(const s8v*)(WfLp + (size_t)(mt * 64 + lane) * 8);
      const s8v b1h = *(const s8v*)(WfHp + (size_t)((16 + mt) * 64 + lane) * 8);
      const s8v b1l = *(const s8v*)(WfLp + (size_t)((16 + mt) * 64 + lane) * 8);
      f4v p = zero4;
      p = MFMA16(a0h, b0h, p);
      p = MFMA16(a1h, b1h, p);
      p = MFMA16(a0h, b0l, p);
      p = MFMA16(a1h, b1l, p);
      p = MFMA16(a0l, b0h, p);
      p = MFMA16(a1l, b1h, p);
#pragma unroll
      for (int r = 0; r < 4; r++) {
        const float arg = fminf(p[r] + ccr[r], ECLAMP);
        const float kv_ = RSQM * __expf(arg) + (RSQM * FEPS);
        hs[mi][r] = bhi(kv_);
        ls[mi][r] = bhi(kv_ - bhif(kv_));
      }
    }
    __syncthreads();  // previous iteration's stage-B readers are done
#pragma unroll
    for (int mi = 0; mi < 4; mi++) {
      const int m = (mg * 4 + mi) * 16 + l15;
      *(ushort4*)&kpH[m][rt * 16 + 4 * g] =
          make_ushort4(hs[mi][0], hs[mi][1], hs[mi][2], hs[mi][3]);
      *(ushort4*)&kpL[m][rt * 16 + 4 * g] =
          make_ushort4(ls[mi][0], ls[mi][1], ls[mi][2], ls[mi][3]);
    }
    {  // publish V fragment: one conflict-free b128 per thread
      u16(*vdst)[64][8] = vhl ? VfL : VfH;
      *(s8v*)&vdst[vct][lane][0] = vf;
    }
    __syncthreads();

    // stage B: A2 = k'^T frags, one ds_read_b128 each
    const s8v A0h = *(const s8v*)&kpH[mtb * 16 + l15][8 * g];
    const s8v A0l = *(const s8v*)&kpL[mtb * 16 + l15][8 * g];
    const s8v A1h = *(const s8v*)&kpH[(mtb + 1) * 16 + l15][8 * g];
    const s8v A1l = *(const s8v*)&kpL[(mtb + 1) * 16 + l15][8 * g];
#pragma unroll
    for (int ct = 0; ct < 4; ct++) {
      const s8v vh = *(const s8v*)&VfH[ct][lane][0];
      const s8v vl = *(const s8v*)&VfL[ct][lane][0];
      acc[0][ct] = MFMA16(A0h, vh, acc[0][ct]);
      acc[0][ct] = MFMA16(A0h, vl, acc[0][ct]);
      acc[0][ct] = MFMA16(A0l, vh, acc[0][ct]);
      acc[1][ct] = MFMA16(A1h, vh, acc[1][ct]);
      acc[1][ct] = MFMA16(A1h, vl, acc[1][ct]);
      acc[1][ct] = MFMA16(A1l, vh, acc[1][ct]);
    }
    acc[0][4] = MFMA16(A0h, oneh, acc[0][4]);  // ksum column (ones, lo = 0)
    acc[0][4] = MFMA16(A0l, oneh, acc[0][4]);
    acc[1][4] = MFMA16(A1h, oneh, acc[1][4]);
    acc[1][4] = MFMA16(A1l, oneh, acc[1][4]);
  }

  float* kvb = kvx + (size_t)bh * (256 * 80);
#pragma unroll
  for (int mi = 0; mi < 2; mi++)
#pragma unroll
    for (int ct = 0; ct < 5; ct++)
#pragma unroll
      for (int r = 0; r < 4; r++) {
        const int m = (mtb + mi) * 16 + 4 * g + r;
        const int c = ct * 16 + l15;
        atomicAdd(&kvb[m * 80 + c], acc[mi][ct][r]);
      }
}

// kvx (summed) -> hi/lo B-fragments, layout [bh][kk(8)][ct(5)][lane(64)][e(8)].
// B[k][j]: k = kk*32 + (lane>>4)*8 + e (the m axis), j = ct*16 + (lane&15).
__global__ __launch_bounds__(512) void fragk_kernel(const float* __restrict__ kvx,
                                                    u16* __restrict__ kvfH,
                                                    u16* __restrict__ kvfL) {
  const int bh = blockIdx.x;
  const float* kb = kvx + (size_t)bh * (256 * 80);
  for (int f = threadIdx.x; f < 20480; f += 512) {
    const int kk = f / 2560;
    const int r1 = f - kk * 2560;
    const int ct = r1 >> 9;
    const int r2 = r1 & 511;
    const int ln = r2 >> 3, e = r2 & 7;
    const int m = kk * 32 + ((ln >> 4) << 3) + e;
    const int c = ct * 16 + (ln & 15);
    const float x = kb[m * 80 + c];
    const u16 hh = f2bf(x);
    kvfH[(size_t)bh * 20480 + f] = hh;
    kvfL[(size_t)bh * 20480 + f] = f2bf(x - bf2f(hh));
  }
}

// Grid 4096 = (bh 64) x (64-row L-tile 64); 512 threads = 8 waves.
// Stage A: q' = RSQM*exp(proj)+RSQM*eps -> hi/lo into qp[l][m] (stride 264).
// Stage B: out[64][80] = q' @ kvx; cols 0-63 = numerator, col 64 = denominator.
__global__ __launch_bounds__(512, 4) void out_kernel(
    const float* __restrict__ qg, const u16* __restrict__ WfH,
    const u16* __restrict__ WfL, const u16* __restrict__ kvfH,
    const u16* __restrict__ kvfL, float* __restrict__ outp) {
  const int bh = blockIdx.x >> 6, lt = blockIdx.x & 63;
  const int b = bh >> 4, h = bh & 15;
  const int tid = threadIdx.x, lane = tid & 63, w = tid >> 6;
  const int l15 = lane & 15, g = lane >> 4;

  __shared__ __align__(16) u16 qpH[64][264];  // [l][m], stride 528 B
  __shared__ __align__(16) u16 qpL[64][264];
  __shared__ float dinv[64];

  const int rt = w & 3, mh = w >> 2;

  {  // ---- stage A ----
    const float* qb = qg + (size_t)(b * NL + lt * 64 + rt * 16 + l15) * ND + h * HDIM;
    const float4 qa0 = *(const float4*)(qb + g * 8);
    const float4 qa1 = *(const float4*)(qb + g * 8 + 4);
    const float4 qa2 = *(const float4*)(qb + 32 + g * 8);
    const float4 qa3 = *(const float4*)(qb + 32 + g * 8 + 4);
    s8v a0h, a0l, a1h, a1l;
    float ss = 0.f;
    mk2t(qa0, qa1, SCALE, a0h, a0l, ss);
    mk2t(qa2, qa3, SCALE, a1h, a1l, ss);
    f4v zero4 = {0.f, 0.f, 0.f, 0.f};
#pragma unroll
    for (int mi = 0; mi < 8; mi++) {
      const int mt = mh * 8 + mi;
      const s8v b0h = *(const s8v*)(WfH + (size_t)(mt * 64 + lane) * 8);
      const s8v b0l = *(const s8v*)(WfL + (size_t)(mt * 64 + lane) * 8);
      const s8v b1h = *(const s8v*)(WfH + (size_t)((16 + mt) * 64 + lane) * 8);
      const s8v b1l = *(const s8v*)(WfL + (size_t)((16 + mt) * 64 + lane) * 8);
      f4v p = zero4;
      p = MFMA16(a0h, b0h, p);
      p = MFMA16(a1h, b1h, p);
      p = MFMA16(a0h, b0l, p);
      p = MFMA16(a1h, b1l, p);
      p = MFMA16(a0l, b0h, p);
      p = MFMA16(a1l, b1h, p);
#pragma unroll
      for (int r = 0; r < 4; r++) {
        // queries: stab = h cancels exactly -> q' = RSQM*exp(proj) + RSQM*eps
        const float arg = fminf(p[r], ECLAMP);
        const float qv = RSQM * __expf(arg) + (RSQM * FEPS);
        qpH[rt * 16 + 4 * g + r][mt * 16 + l15] = bhi(qv);
        qpL[rt * 16 + 4 * g + r][mt * 16 + l15] = bhi(qv - bhif(qv));
      }
    }
  }
  __syncthreads();

  // ---- stage B ---- waves w<4: cts {0,1,4} (rt rows); w>=4: cts {2,3}
  const int ctA = (w < 4) ? 0 : 2;
  const int ctB = ctA + 1;
  f4v o0 = {0.f, 0.f, 0.f, 0.f}, o1 = o0, o2 = o0;
  const size_t fb = (size_t)bh * (8 * 5 * 512);
#pragma unroll
  for (int kk = 0; kk < 8; kk++) {
    const s8v A2h = *(const s8v*)&qpH[rt * 16 + l15][kk * 32 + 8 * g];
    const s8v A2l = *(const s8v*)&qpL[rt * 16 + l15][kk * 32 + 8 * g];
    const size_t bA = fb + (size_t)((kk * 5 + ctA) * 64 + lane) * 8;
    const s8v BAh = *(const s8v*)(kvfH + bA);
    const s8v BAl = *(const s8v*)(kvfL + bA);
    o0 = MFMA16(A2h, BAh, o0);
    o0 = MFMA16(A2h, BAl, o0);
    o0 = MFMA16(A2l, BAh, o0);
    const size_t bB = fb + (size_t)((kk * 5 + ctB) * 64 + lane) * 8;
    const s8v BBh = *(const s8v*)(kvfH + bB);
    const s8v BBl = *(const s8v*)(kvfL + bB);
    o1 = MFMA16(A2h, BBh, o1);
    o1 = MFMA16(A2h, BBl, o1);
    o1 = MFMA16(A2l, BBh, o1);
    if (w < 4) {
      const size_t bC = fb + (size_t)((kk * 5 + 4) * 64 + lane) * 8;
      const s8v BCh = *(const s8v*)(kvfH + bC);
      const s8v BCl = *(const s8v*)(kvfL + bC);
      o2 = MFMA16(A2h, BCh, o2);
      o2 = MFMA16(A2h, BCl, o2);
      o2 = MFMA16(A2l, BCh, o2);
    }
  }
  if (w < 4 && l15 == 0) {  // denominator = column 64
#pragma unroll
    for (int r = 0; r < 4; r++) {
      float d = o2[r];
      if (fabsf(d) <= FEPS) d += 2.0f * FEPS;
      dinv[rt * 16 + 4 * g + r] = 1.0f / d;
    }
  }
  __syncthreads();
  {
    float* ob = outp + (size_t)(b * NL + lt * 64) * ND + h * HDIM;
#pragma unroll
    for (int r = 0; r < 4; r++) {
      const int row = rt * 16 + 4 * g + r;
      const float di = dinv[row];
      ob[(size_t)row * ND + ctA * 16 + l15] = o0[r] * di;
      ob[(size_t)row * ND + ctB * 16 + l15] = o1[r] * di;
    }
  }
}

extern "C" void kernel_launch(void* const* d_in, const int* in_sizes, int n_in,
                              void* d_out, int out_size, void* d_ws, size_t ws_size,
                              hipStream_t stream) {
  const float* q = (const float*)d_in[0];
  const float* k = (const float*)d_in[1];
  const float* v = (const float*)d_in[2];
  const float* w = (const float*)d_in[3];
  float* out = (float*)d_out;

  // workspace: WfH 32KB | WfL 32KB | kvx 5.24MB | kvfH 2.62MB | kvfL 2.62MB
  // total ~10.1 MB
  u16* WfH = (u16*)d_ws;
  u16* WfL = WfH + 16384;
  float* kvx = (float*)((char*)d_ws + 65536);
  u16* kvfH = (u16*)((char*)d_ws + 65536 + (size_t)64 * 256 * 80 * 4);
  u16* kvfL = kvfH + (size_t)64 * 20480;

  prep_kernel<<<32, 512, 0, stream>>>(w, WfH, WfL, kvx);
  kv_kernel<<<512, 512, 0, stream>>>(k, v, WfH, WfL, kvx);
  fragk_kernel<<<64, 512, 0, stream>>>(kvx, kvfH, kvfL);
  out_kernel<<<4096, 512, 0, stream>>>(q, WfH, WfL, kvfH, kvfL, out);
}